// Round 5
// baseline (465.284 us; speedup 1.0000x reference)
//
#include <hip/hip_runtime.h>
#include <stdint.h>

typedef unsigned short ushort_t;
typedef unsigned int   uint_t;

__device__ __forceinline__ float b2f(ushort_t u) {
    return __uint_as_float(((uint_t)u) << 16);
}
__device__ __forceinline__ float lrelu(float s) {
    return s >= 0.f ? s : 0.2f * s;
}

// One block per graph (grid 4096). Thread t owns output column e = t.
// h[j][t] for all 24 joints lives in this thread's registers; wave == head,
// so a_s/a_d are wave-level shuffle reductions; the tridiagonal softmax
// aggregation is register-local. Only x transits LDS (broadcast reads).
// OUTPUT: fp32 (the reference's output dtype).
__global__ __launch_bounds__(256)
void gat_kernel(const void* __restrict__ xin,
                const void* __restrict__ Win,
                const void* __restrict__ asin,
                const void* __restrict__ adin,
                const void* __restrict__ biin,
                const int*  __restrict__ ei,
                float*      __restrict__ out,
                int E0)
{
    __shared__ __align__(16) float x_f[24 * 256];   // 24 KB
    __shared__ int has_up[24], has_dn[24];
    __shared__ int flag_sm;

    const int t = threadIdx.x;
    const int g = blockIdx.x;

    // ---- float dtype probe (verified): low half-word exponent bits.
    // bf16 pair -> low half is a full bf16, exp in [100,150] (hit ~64/64).
    // fp32 -> bits 14:7 are mid-mantissa, ~uniform (hit ~13/64). Threshold 40.
    if (t < 64) {
        uint_t wv  = ((const uint_t*)xin)[t];
        int elo    = (int)((wv >> 7) & 0xFFu);
        int pred   = (elo >= 100 && elo <= 150) ? 1 : 0;
        unsigned long long m = __ballot(pred);
        if (t == 0) flag_sm = (__popcll(m) >= 40) ? 1 : 0;   // 1 => bf16 inputs
    }
    if (t < 24) { has_up[t] = 0; has_dn[t] = 0; }
    __syncthreads();

    // ---- edge_index parse, robust to int32 vs int64 storage.
    {
        const int e64 = (ei[1] == 0 && ei[3] == 0 && ei[5] == 0) ? 1 : 0;
        if (t < E0) {
            int s, d;
            if (e64) { s = ei[2 * t];  d = ei[2 * E0 + 2 * t]; }
            else     { s = ei[t];      d = ei[E0 + t]; }
            if (s == d - 1) has_up[d] = 1;
            if (s == d + 1) has_dn[d] = 1;
        }
    }
    const int isbf16 = flag_sm;

    // ---- stage x[g] into LDS as fp32 (coalesced)
    if (isbf16) {
        const ushort_t* xg = (const ushort_t*)xin + (size_t)g * 6144;
#pragma unroll
        for (int i = 0; i < 6; ++i) {
            int c = i * 256 + t, row = c >> 6, off = (c & 63) * 4;
            ushort4 v = *(const ushort4*)&xg[row * 256 + off];
            float4 f;
            f.x = b2f(v.x); f.y = b2f(v.y); f.z = b2f(v.z); f.w = b2f(v.w);
            *(float4*)&x_f[row * 256 + off] = f;
        }
    } else {
        const float* xg = (const float*)xin + (size_t)g * 6144;
#pragma unroll
        for (int i = 0; i < 6; ++i) {
            int c = i * 256 + t, row = c >> 6, off = (c & 63) * 4;
            *(float4*)&x_f[row * 256 + off] = *(const float4*)&xg[row * 256 + off];
        }
    }
    __syncthreads();   // covers x_f staging, adjacency writes, flag_sm

    // ---- h[j][t] = sum_k x[j][k] * W[k][t]  (fp32 VALU, k-chunks of 4)
    float acc[24];
#pragma unroll
    for (int j = 0; j < 24; ++j) acc[j] = 0.f;

    if (isbf16) {
        const ushort_t* Wp = (const ushort_t*)Win;
        for (int kc = 0; kc < 64; ++kc) {
            float w0 = b2f(Wp[(kc * 4 + 0) * 256 + t]);
            float w1 = b2f(Wp[(kc * 4 + 1) * 256 + t]);
            float w2 = b2f(Wp[(kc * 4 + 2) * 256 + t]);
            float w3 = b2f(Wp[(kc * 4 + 3) * 256 + t]);
#pragma unroll
            for (int j = 0; j < 24; ++j) {
                float4 xv = *(const float4*)&x_f[j * 256 + kc * 4];
                acc[j] += xv.x * w0 + xv.y * w1 + xv.z * w2 + xv.w * w3;
            }
        }
    } else {
        const float* Wp = (const float*)Win;
        for (int kc = 0; kc < 64; ++kc) {
            float w0 = Wp[(kc * 4 + 0) * 256 + t];
            float w1 = Wp[(kc * 4 + 1) * 256 + t];
            float w2 = Wp[(kc * 4 + 2) * 256 + t];
            float w3 = Wp[(kc * 4 + 3) * 256 + t];
#pragma unroll
            for (int j = 0; j < 24; ++j) {
                float4 xv = *(const float4*)&x_f[j * 256 + kc * 4];
                acc[j] += xv.x * w0 + xv.y * w1 + xv.z * w2 + xv.w * w3;
            }
        }
    }

    // ---- per-wave (== per-head) attention logits via 64-lane butterfly
    float att_sv, att_dv, bias_v;
    if (isbf16) {
        att_sv = b2f(((const ushort_t*)asin)[t]);
        att_dv = b2f(((const ushort_t*)adin)[t]);
        bias_v = b2f(((const ushort_t*)biin)[t]);
    } else {
        att_sv = ((const float*)asin)[t];
        att_dv = ((const float*)adin)[t];
        bias_v = ((const float*)biin)[t];
    }

    float asv[24], adv[24];
#pragma unroll
    for (int j = 0; j < 24; ++j) {
        float ps = acc[j] * att_sv;
        float pd = acc[j] * att_dv;
#pragma unroll
        for (int s = 1; s < 64; s <<= 1) {
            ps += __shfl_xor(ps, s);
            pd += __shfl_xor(pd, s);
        }
        asv[j] = ps;   // a_s[j] for this head, uniform across the wave
        adv[j] = pd;
    }

    // ---- 3-neighbor softmax + aggregation (register-local) + bias, fp32 out
    float* og = out + (size_t)g * 6144 + t;
#pragma unroll
    for (int j = 0; j < 24; ++j) {
        const bool hu = has_up[j] != 0;
        const bool hd = has_dn[j] != 0;
        const float ad = adv[j];
        const float aU = (j > 0)  ? asv[j - 1] : 0.f;
        const float aD = (j < 23) ? asv[j + 1] : 0.f;
        const float sU = hu ? lrelu(aU + ad) : -1e30f;
        const float sS =      lrelu(asv[j] + ad);
        const float sD = hd ? lrelu(aD + ad) : -1e30f;
        const float mx = fmaxf(sS, fmaxf(sU, sD));
        const float eU = __expf(sU - mx);
        const float eS = __expf(sS - mx);
        const float eD = __expf(sD - mx);
        const float inv = 1.f / (eU + eS + eD);
        const float hm = (j > 0)  ? acc[j - 1] : 0.f;
        const float hp = (j < 23) ? acc[j + 1] : 0.f;
        const float val = bias_v + inv * (eU * hm + eS * acc[j] + eD * hp);
        og[j * 256] = val;
    }
}

extern "C" void kernel_launch(void* const* d_in, const int* in_sizes, int n_in,
                              void* d_out, int out_size, void* d_ws, size_t ws_size,
                              hipStream_t stream) {
    const void* x  = d_in[0];
    const void* W  = d_in[1];
    const void* as = d_in[2];
    const void* ad = d_in[3];
    const void* bi = d_in[4];
    const int*  ei = (const int*)d_in[5];
    float*      o  = (float*)d_out;

    const int n5 = in_sizes[5];
    const int E0 = (n5 == 184) ? 46 : n5 / 2;   // 46 directed edges
    const int G  = in_sizes[0] / 6144;          // 4096 graphs

    hipLaunchKernelGGL(gat_kernel, dim3(G), dim3(256), 0, stream,
                       x, W, as, ad, bi, ei, o, E0);
}